// Round 3
// baseline (236.631 us; speedup 1.0000x reference)
//
#include <hip/hip_runtime.h>
#include <hip/hip_bf16.h>

#define FH 200
#define FW 200
#define FC 1024
#define POOL 7

typedef float vf4 __attribute__((ext_vector_type(4)));

__device__ __forceinline__ vf4 lerp4(vf4 a, vf4 b, float w1) {
    return a * (1.0f - w1) + b * w1;
}

// One block per (n, py): 7 pooled positions, 256 threads x float4 = 1024 ch.
// All loads for the row issued before any compute -> up to 26 loads in flight.
__global__ __launch_bounds__(256) void roi_pool_kernel(
    const float* __restrict__ feat,   // (H, W, C)
    const int*   __restrict__ rois,   // (N, 4) = x0, y0, w, h
    float*       __restrict__ out,    // (N, POOL, POOL, C)
    int N)
{
    const int blk = blockIdx.x;
    const int n  = blk / POOL;
    const int py = blk % POOL;
    if (n >= N) return;

    const int x0 = rois[4 * n + 0];
    const int y0 = rois[4 * n + 1];
    const int w  = rois[4 * n + 2];
    const int h  = rois[4 * n + 3];

    // Vertical sample (wave-uniform), matching reference arithmetic.
    const float ry = (float)py * ((float)h / (float)POOL);
    const int   ylo = (int)floorf(ry);
    const float fy  = ry - (float)ylo;
    const int   yhi = min(ylo + 1, h - 1);
    const int   iy0 = min(max(y0 + ylo, 0), FH - 1);
    const int   iy1 = min(max(y0 + yhi, 0), FH - 1);

    // Horizontal samples for all 7 px (wave-uniform).
    const float wOverP = (float)w / (float)POOL;
    int   ix0[POOL], ix1[POOL];
    float fx[POOL];
#pragma unroll
    for (int px = 0; px < POOL; ++px) {
        const float rx  = (float)px * wOverP;
        const int   xlo = (int)floorf(rx);
        fx[px]          = rx - (float)xlo;
        const int   xhi = min(xlo + 1, w - 1);
        ix0[px] = min(max(x0 + xlo, 0), FW - 1);
        ix1[px] = min(max(x0 + xhi, 0), FW - 1);
    }

    const int t = threadIdx.x;
    const float* rowTop = feat + (size_t)iy0 * (size_t)(FW * FC);
    const float* rowBot = feat + (size_t)iy1 * (size_t)(FW * FC);
    vf4* o = (vf4*)(out + (size_t)blk * (size_t)(POOL * FC));

    if (fy == 0.0f) {
        // Bottom row has weight 0 (reference: top*1 + bot*0, bot finite) — skip it.
        vf4 a[POOL], b[POOL];
#pragma unroll
        for (int px = 0; px < POOL; ++px) {
            a[px] = ((const vf4*)(rowTop + (size_t)ix0[px] * FC))[t];
            if (px > 0)  // px==0: fx==0 exactly, right column weight 0
                b[px] = ((const vf4*)(rowTop + (size_t)ix1[px] * FC))[t];
        }
#pragma unroll
        for (int px = 0; px < POOL; ++px) {
            vf4 r = (px == 0) ? a[0] : lerp4(a[px], b[px], fx[px]);
            __builtin_nontemporal_store(r, &o[px * (FC / 4) + t]);
        }
    } else {
        vf4 a[POOL], b[POOL], c[POOL], d[POOL];
#pragma unroll
        for (int px = 0; px < POOL; ++px) {
            a[px] = ((const vf4*)(rowTop + (size_t)ix0[px] * FC))[t];
            c[px] = ((const vf4*)(rowBot + (size_t)ix0[px] * FC))[t];
            if (px > 0) {
                b[px] = ((const vf4*)(rowTop + (size_t)ix1[px] * FC))[t];
                d[px] = ((const vf4*)(rowBot + (size_t)ix1[px] * FC))[t];
            }
        }
#pragma unroll
        for (int px = 0; px < POOL; ++px) {
            vf4 top, bot;
            if (px == 0) { top = a[0]; bot = c[0]; }
            else {
                top = lerp4(a[px], b[px], fx[px]);
                bot = lerp4(c[px], d[px], fx[px]);
            }
            const vf4 r = lerp4(top, bot, fy);
            __builtin_nontemporal_store(r, &o[px * (FC / 4) + t]);
        }
    }
}

extern "C" void kernel_launch(void* const* d_in, const int* in_sizes, int n_in,
                              void* d_out, int out_size, void* d_ws, size_t ws_size,
                              hipStream_t stream) {
    const float* feat = (const float*)d_in[0];   // (1, 200, 200, 1024) fp32
    const int*   rois = (const int*)d_in[1];     // (300, 4) int32
    float* out = (float*)d_out;                  // (300, 7, 7, 1024) fp32

    const int N = in_sizes[1] / 4;
    const int blocks = N * POOL;
    roi_pool_kernel<<<blocks, 256, 0, stream>>>(feat, rois, out, N);
}

// Round 4
// 226.467 us; speedup vs baseline: 1.0449x; 1.0449x over previous
//
#include <hip/hip_runtime.h>
#include <hip/hip_bf16.h>

#define FH 200
#define FW 200
#define FC 1024
#define POOL 7

typedef float vf4 __attribute__((ext_vector_type(4)));

__device__ __forceinline__ vf4 lerp4(vf4 a, vf4 b, float w1) {
    return a * (1.0f - w1) + b * w1;
}

// One block per (n, py, px). 256 threads x float4 = 1024 channels.
// Wave-uniform branches skip weight-0 loads (px==0 -> fx==0, py==0 -> fy==0):
// avg 3.45 loads/position instead of 4 (-13.8% issued reads).
__global__ __launch_bounds__(256) void roi_pool_kernel(
    const float* __restrict__ feat,   // (H, W, C)
    const int*   __restrict__ rois,   // (N, 4) = x0, y0, w, h
    float*       __restrict__ out,    // (N, POOL, POOL, C)
    int N)
{
    const int blk = blockIdx.x;
    const int n  = blk / (POOL * POOL);
    if (n >= N) return;
    const int r  = blk % (POOL * POOL);
    const int py = r / POOL;
    const int px = r % POOL;

    const int x0 = rois[4 * n + 0];
    const int y0 = rois[4 * n + 1];
    const int w  = rois[4 * n + 2];
    const int h  = rois[4 * n + 3];

    // Match reference arithmetic order exactly (fp32 throughout).
    const float ry = (float)py * ((float)h / (float)POOL);
    const float rx = (float)px * ((float)w / (float)POOL);
    const int ylo = (int)floorf(ry);
    const int xlo = (int)floorf(rx);
    const float fy = ry - (float)ylo;
    const float fx = rx - (float)xlo;
    const int yhi = min(ylo + 1, h - 1);
    const int xhi = min(xlo + 1, w - 1);

    const int iy0 = min(max(y0 + ylo, 0), FH - 1);
    const int iy1 = min(max(y0 + yhi, 0), FH - 1);
    const int ix0 = min(max(x0 + xlo, 0), FW - 1);
    const int ix1 = min(max(x0 + xhi, 0), FW - 1);

    const int t = threadIdx.x;
    const vf4* p00 = (const vf4*)(feat + ((size_t)iy0 * FW + ix0) * FC);
    const vf4* p01 = (const vf4*)(feat + ((size_t)iy0 * FW + ix1) * FC);
    const vf4* p10 = (const vf4*)(feat + ((size_t)iy1 * FW + ix0) * FC);
    const vf4* p11 = (const vf4*)(feat + ((size_t)iy1 * FW + ix1) * FC);

    const bool needX = (fx != 0.0f);   // wave-uniform
    const bool needY = (fy != 0.0f);   // wave-uniform

    // Issue every needed load before any compute.
    vf4 a, b, c, d;
    a = p00[t];
    if (needX) b = p01[t];
    if (needY) c = p10[t];
    if (needX && needY) d = p11[t];

    vf4 top = needX ? lerp4(a, b, fx) : a;
    vf4 res;
    if (needY) {
        vf4 bot = needX ? lerp4(c, d, fx) : c;
        res = lerp4(top, bot, fy);
    } else {
        res = top;
    }

    float* o = out + ((size_t)blk) * FC + 4 * t;
    __builtin_nontemporal_store(res, (vf4*)o);
}

extern "C" void kernel_launch(void* const* d_in, const int* in_sizes, int n_in,
                              void* d_out, int out_size, void* d_ws, size_t ws_size,
                              hipStream_t stream) {
    const float* feat = (const float*)d_in[0];   // (1, 200, 200, 1024) fp32
    const int*   rois = (const int*)d_in[1];     // (300, 4) int32
    float* out = (float*)d_out;                  // (300, 7, 7, 1024) fp32

    const int N = in_sizes[1] / 4;
    const int blocks = N * POOL * POOL;
    roi_pool_kernel<<<blocks, 256, 0, stream>>>(feat, rois, out, N);
}